// Round 3
// baseline (150.175 us; speedup 1.0000x reference)
//
#include <hip/hip_runtime.h>
#include <hip/hip_bf16.h>

#define NB 4
#define NC 128
#define NCI 64
#define NH 96
#define NQ 9216
#define NKV 2304

typedef __bf16 bf8 __attribute__((ext_vector_type(8)));
typedef float f4 __attribute__((ext_vector_type(4)));
typedef unsigned short u16t;
typedef unsigned int u32t;
typedef u32t u32x2 __attribute__((ext_vector_type(2)));
typedef u32t u32x4 __attribute__((ext_vector_type(4)));

static __device__ __forceinline__ u16t f2bf(float f){
  u32t u = __builtin_bit_cast(u32t, f);
  u = (u + 0x7fffu + ((u >> 16) & 1u)) >> 16;
  return (u16t)u;
}

static __device__ __forceinline__ f4 mfma16(bf8 a, bf8 b, f4 c){
  return __builtin_amdgcn_mfma_f32_16x16x32_bf16(a, b, c, 0, 0, 0);
}

// ---------------------------------------------------------------------------
// Kernel 1: weights -> bf16, fold BN into alpha/beta2 (32 blocks)
// ---------------------------------------------------------------------------
__global__ __launch_bounds__(256) void prep_weights(
    const float* __restrict__ g_w, const float* __restrict__ theta_w,
    const float* __restrict__ phi_w, const float* __restrict__ W_w,
    const float* __restrict__ W_b, const float* __restrict__ bn_gamma,
    const float* __restrict__ bn_beta, const float* __restrict__ bn_mean,
    const float* __restrict__ bn_var,
    u16t* __restrict__ wt_theta, u16t* __restrict__ wt_phi,
    u16t* __restrict__ wt_g, u16t* __restrict__ wt_W,
    float* __restrict__ alpha, float* __restrict__ beta2)
{
  int i = blockIdx.x * 256 + threadIdx.x;
  wt_theta[i] = f2bf(theta_w[i]);
  wt_phi[i]   = f2bf(phi_w[i]);
  wt_g[i]     = f2bf(g_w[i]);
  wt_W[i]     = f2bf(W_w[i]);
  if (blockIdx.x == 0 && threadIdx.x < 128){
    int t = threadIdx.x;
    float inv = bn_gamma[t] * rsqrtf(bn_var[t] + 1e-5f);
    alpha[t] = inv;
    beta2[t] = W_b[t]*inv + bn_beta[t] - bn_mean[t]*inv;
  }
}

// ---------------------------------------------------------------------------
// Kernel 2: theta/phi/g 1x1 convs via MFMA + fused 2x2 maxpool for phi/g.
// ---------------------------------------------------------------------------
__global__ __launch_bounds__(256) void conv3_pool(
    const float* __restrict__ x,
    const u16t* __restrict__ wt_theta, const u16t* __restrict__ wt_phi,
    const u16t* __restrict__ wt_g,
    const float* __restrict__ theta_b, const float* __restrict__ phi_b,
    const float* __restrict__ g_b,
    u16t* __restrict__ theta, u16t* __restrict__ phi, u16t* __restrict__ g_t)
{
  __shared__ __align__(16) u16t xt[64][136];   // [linear pixel][c]
  const int blk = blockIdx.x;
  const int batch = blk / 144;
  const int t144 = blk % 144;
  const int ph = t144 / 3;
  const int pw0 = (t144 % 3) * 16;
  const int t = threadIdx.x;
  const float* xb = x + (size_t)batch * NC * NQ;

  #pragma unroll
  for (int i = 0; i < 32; ++i){
    int idx = i*256 + t;
    int c = idx >> 6;
    int pl = idx & 63;                         // linear: (row<<5)|col
    int q = (ph*2 + (pl>>5))*NH + pw0*2 + (pl & 31);
    xt[pl][c] = f2bf(xb[(size_t)c*NQ + q]);
  }
  __syncthreads();

  const int w = t >> 6, l = t & 63, lm = l & 15, lg = l >> 4;
  auto PL = [](int pxi){
    return (((pxi>>1)&1) << 5) + 8*(pxi>>4) + 2*((pxi>>2)&3) + (pxi&1);
  };
  bf8 a[4];
  #pragma unroll
  for (int k = 0; k < 4; ++k)
    a[k] = *(const bf8*)&xt[PL(w*16 + lm)][k*32 + lg*8];

  int qrow[4];
  #pragma unroll
  for (int r = 0; r < 4; ++r){
    int pxi = w*16 + lg*4 + r;
    qrow[r] = (ph*2 + ((pxi>>1)&1))*NH + (pw0 + 4*(pxi>>4) + ((pxi>>2)&3))*2 + (pxi&1);
  }
  const int kv = ph*48 + pw0 + 4*w + lg;

  { // theta (no pool)
    u16t* th = theta + (size_t)batch * NQ * 64;
    #pragma unroll
    for (int s = 0; s < 4; ++s){
      float bv = theta_b[s*16 + lm];
      f4 D = {bv, bv, bv, bv};
      #pragma unroll
      for (int k = 0; k < 4; ++k){
        bf8 b = *(const bf8*)&wt_theta[(s*16 + lm)*128 + k*32 + lg*8];
        D = mfma16(a[k], b, D);
      }
      #pragma unroll
      for (int r = 0; r < 4; ++r)
        th[(size_t)qrow[r]*64 + s*16 + lm] = f2bf(D[r]);
    }
  }
  { // phi (pooled)
    u16t* pp = phi + (size_t)batch * NKV * 64;
    #pragma unroll
    for (int s = 0; s < 4; ++s){
      float bv = phi_b[s*16 + lm];
      f4 D = {bv, bv, bv, bv};
      #pragma unroll
      for (int k = 0; k < 4; ++k){
        bf8 b = *(const bf8*)&wt_phi[(s*16 + lm)*128 + k*32 + lg*8];
        D = mfma16(a[k], b, D);
      }
      float mx = fmaxf(fmaxf(D[0], D[1]), fmaxf(D[2], D[3]));
      pp[(size_t)kv*64 + s*16 + lm] = f2bf(mx);
    }
  }
  { // g (pooled, transposed store)
    u16t* gt = g_t + (size_t)batch * 64 * NKV;
    #pragma unroll
    for (int s = 0; s < 4; ++s){
      float bv = g_b[s*16 + lm];
      f4 D = {bv, bv, bv, bv};
      #pragma unroll
      for (int k = 0; k < 4; ++k){
        bf8 b = *(const bf8*)&wt_g[(s*16 + lm)*128 + k*32 + lg*8];
        D = mfma16(a[k], b, D);
      }
      float mx = fmaxf(fmaxf(D[0], D[1]), fmaxf(D[2], D[3]));
      gt[(size_t)(s*16 + lm)*NKV + kv] = f2bf(mx);
    }
  }
}

// ---------------------------------------------------------------------------
// Kernel 3: fused attention + W-conv + BN + residual.
// 512 threads = 8 waves. Wave w: qh=w>>2 (32-query half, M_rep=2),
// kh=w&3 (KV quarter, 9 of 36 tiles). Swapped QK (mfma(phi,theta)) puts the
// key dim in registers -> packed b64 P writes, 2-shuffle row sums.
// 4-quarter Y combine via 2-stage f32 LDS reduction in the dead p_lds region.
// ---------------------------------------------------------------------------
__global__ __launch_bounds__(512) void attn_fused(
    const u16t* __restrict__ theta, const u16t* __restrict__ phi,
    const u16t* __restrict__ g_t, const u16t* __restrict__ wt_W,
    const float* __restrict__ alpha, const float* __restrict__ beta2,
    const float* __restrict__ x, float* __restrict__ out)
{
  __shared__ __align__(16) char region[36864];   // p_lds -> yp -> out_lds
  __shared__ __align__(16) u16t y_lds[64][72];
  __shared__ float sums[8][32];
  const int blk = blockIdx.x;
  const int batch = blk / 144;
  const int qb = (blk % 144) * 64;
  const int t = threadIdx.x;
  const int w = t >> 6, l = t & 63, lm = l & 15, lg = l >> 4;
  const int qh = w >> 2, kh = w & 3;

  const u16t* th = theta + ((size_t)batch*NQ + qb + qh*32)*64;
  bf8 a[2][2];
  #pragma unroll
  for (int mr = 0; mr < 2; ++mr){
    a[mr][0] = *(const bf8*)&th[(mr*16 + lm)*64 + lg*8];
    a[mr][1] = *(const bf8*)&th[(mr*16 + lm)*64 + lg*8 + 32];
  }
  const u16t* phb = phi + (size_t)batch*NKV*64;
  const u16t* gtb = g_t + (size_t)batch*64*NKV;

  u16t (*p_lds)[72] = (u16t (*)[72])(region + w*4608);  // per-wave [32][72]

  f4 Y[2][4];
  #pragma unroll
  for (int mr = 0; mr < 2; ++mr)
    #pragma unroll
    for (int s = 0; s < 4; ++s)
      Y[mr][s] = f4{0.f, 0.f, 0.f, 0.f};
  float lsum[2] = {0.f, 0.f};

  for (int kt = kh*9; kt < kh*9 + 9; ++kt){
    const int kb = kt*64;
    bf8 bp[4][2];
    #pragma unroll
    for (int tt = 0; tt < 4; ++tt){
      const u16t* pk = phb + (size_t)(kb + tt*16 + lm)*64;
      bp[tt][0] = *(const bf8*)&pk[lg*8];
      bp[tt][1] = *(const bf8*)&pk[lg*8 + 32];
    }
    bf8 bg[4][2];
    #pragma unroll
    for (int s = 0; s < 4; ++s){
      const u16t* gr = gtb + (size_t)(s*16 + lm)*NKV + kb;
      bg[s][0] = *(const bf8*)&gr[lg*8];
      bg[s][1] = *(const bf8*)&gr[lg*8 + 32];
    }
    // swapped QK: D[key][query] -> lane lm holds query lm, keys tt*16+lg*4+r
    f4 S[2][4];
    #pragma unroll
    for (int tt = 0; tt < 4; ++tt)
      #pragma unroll
      for (int mr = 0; mr < 2; ++mr){
        f4 z = {0.f, 0.f, 0.f, 0.f};
        z = mfma16(bp[tt][0], a[mr][0], z);
        S[mr][tt] = mfma16(bp[tt][1], a[mr][1], z);
      }
    // P = exp(S-30), packed b64 writes (k-adjacent pairs live in one lane)
    #pragma unroll
    for (int mr = 0; mr < 2; ++mr)
      #pragma unroll
      for (int tt = 0; tt < 4; ++tt){
        float p0 = __expf(S[mr][tt][0] - 30.0f);
        float p1 = __expf(S[mr][tt][1] - 30.0f);
        float p2 = __expf(S[mr][tt][2] - 30.0f);
        float p3 = __expf(S[mr][tt][3] - 30.0f);
        lsum[mr] += (p0 + p1) + (p2 + p3);
        u32t lo = (u32t)f2bf(p0) | ((u32t)f2bf(p1) << 16);
        u32t hi = (u32t)f2bf(p2) | ((u32t)f2bf(p3) << 16);
        *(u32x2*)&p_lds[mr*16 + lm][tt*16 + lg*4] = u32x2{lo, hi};
      }
    #pragma unroll
    for (int mr = 0; mr < 2; ++mr){
      bf8 pa0 = *(const bf8*)&p_lds[mr*16 + lm][lg*8];
      bf8 pa1 = *(const bf8*)&p_lds[mr*16 + lm][lg*8 + 32];
      #pragma unroll
      for (int s = 0; s < 4; ++s){
        Y[mr][s] = mfma16(pa0, bg[s][0], Y[mr][s]);
        Y[mr][s] = mfma16(pa1, bg[s][1], Y[mr][s]);
      }
    }
  }

  // per-query partial sums: reduce across the 4 lg groups
  #pragma unroll
  for (int mr = 0; mr < 2; ++mr){
    float sv = lsum[mr];
    sv += __shfl_xor(sv, 16);
    sv += __shfl_xor(sv, 32);
    if (lg == 0) sums[w][mr*16 + lm] = sv;
  }

  __syncthreads();                       // p_lds dead -> yp [128][66] f32
  float (*yp)[66] = (float (*)[66])region;
  if (kh < 2){
    #pragma unroll
    for (int mr = 0; mr < 2; ++mr)
      #pragma unroll
      for (int s = 0; s < 4; ++s)
        #pragma unroll
        for (int r = 0; r < 4; ++r)
          yp[kh*64 + qh*32 + mr*16 + lg*4 + r][s*16 + lm] = Y[mr][s][r];
  }
  __syncthreads();
  if (kh >= 2){
    #pragma unroll
    for (int mr = 0; mr < 2; ++mr)
      #pragma unroll
      for (int s = 0; s < 4; ++s)
        #pragma unroll
        for (int r = 0; r < 4; ++r)
          yp[(kh-2)*64 + qh*32 + mr*16 + lg*4 + r][s*16 + lm] += Y[mr][s][r];
  }
  __syncthreads();

  // combine parities, normalize, pack bf16 y into y_lds
  {
    int row = t >> 3, cg = t & 7;
    int i = row & 31, q2 = row >> 5;
    float tot = sums[q2*4 + 0][i] + sums[q2*4 + 1][i]
              + sums[q2*4 + 2][i] + sums[q2*4 + 3][i];
    float inv = 1.0f / tot;
    u32x4 wd;
    #pragma unroll
    for (int jj = 0; jj < 4; ++jj){
      float v0 = (yp[row][cg*8 + jj*2]     + yp[64 + row][cg*8 + jj*2])     * inv;
      float v1 = (yp[row][cg*8 + jj*2 + 1] + yp[64 + row][cg*8 + jj*2 + 1]) * inv;
      wd[jj] = (u32t)f2bf(v0) | ((u32t)f2bf(v1) << 16);
    }
    *(u32x4*)&y_lds[row][cg*8] = wd;
  }
  __syncthreads();                       // yp dead -> out_lds [64][130] f32
  float (*ol)[130] = (float (*)[130])region;

  // W conv: wave w owns output channels w*16..w*16+15, all 64 queries
  {
    const u16t* wr = wt_W + (w*16 + lm)*64;
    bf8 b0 = *(const bf8*)&wr[lg*8];
    bf8 b1 = *(const bf8*)&wr[lg*8 + 32];
    #pragma unroll
    for (int mr2 = 0; mr2 < 4; ++mr2){
      bf8 a0 = *(const bf8*)&y_lds[mr2*16 + lm][lg*8];
      bf8 a1 = *(const bf8*)&y_lds[mr2*16 + lm][lg*8 + 32];
      f4 z = {0.f, 0.f, 0.f, 0.f};
      z = mfma16(a0, b0, z);
      z = mfma16(a1, b1, z);
      #pragma unroll
      for (int r = 0; r < 4; ++r)
        ol[mr2*16 + lg*4 + r][w*16 + lm] = z[r];
    }
  }
  __syncthreads();

  // BN + residual, coalesced stores (512 threads: q=t&63, c-range by t>>6)
  const float* xb = x + (size_t)batch*NC*NQ + qb;
  float* ob = out + (size_t)batch*NC*NQ + qb;
  const int q = t & 63;
  const int cg2 = t >> 6;
  #pragma unroll
  for (int k = 0; k < 16; ++k){
    int c = cg2*16 + k;
    float v = ol[q][c];
    ob[(size_t)c*NQ + q] = v*alpha[c] + beta2[c] + xb[(size_t)c*NQ + q];
  }
}

// ---------------------------------------------------------------------------
extern "C" void kernel_launch(void* const* d_in, const int* in_sizes, int n_in,
                              void* d_out, int out_size, void* d_ws, size_t ws_size,
                              hipStream_t stream)
{
  const float* x       = (const float*)d_in[0];
  const float* g_w     = (const float*)d_in[1];
  const float* g_b     = (const float*)d_in[2];
  const float* theta_w = (const float*)d_in[3];
  const float* theta_b = (const float*)d_in[4];
  const float* phi_w   = (const float*)d_in[5];
  const float* phi_b   = (const float*)d_in[6];
  const float* W_w     = (const float*)d_in[7];
  const float* W_b     = (const float*)d_in[8];
  const float* bn_g    = (const float*)d_in[9];
  const float* bn_b    = (const float*)d_in[10];
  const float* bn_m    = (const float*)d_in[11];
  const float* bn_v    = (const float*)d_in[12];
  float* out = (float*)d_out;

  char* ws = (char*)d_ws;
  size_t off = 0;
  u16t* theta = (u16t*)(ws + off); off += (size_t)NB*NQ*64*2;
  u16t* phi   = (u16t*)(ws + off); off += (size_t)NB*NKV*64*2;
  u16t* g_t   = (u16t*)(ws + off); off += (size_t)NB*64*NKV*2;
  u16t* wt_theta = (u16t*)(ws + off); off += 64*128*2;
  u16t* wt_phi   = (u16t*)(ws + off); off += 64*128*2;
  u16t* wt_g     = (u16t*)(ws + off); off += 64*128*2;
  u16t* wt_W     = (u16t*)(ws + off); off += 128*64*2;
  float* alpha = (float*)(ws + off); off += 128*4;
  float* beta2 = (float*)(ws + off); off += 128*4;
  if (off > ws_size) return;

  prep_weights<<<32, 256, 0, stream>>>(g_w, theta_w, phi_w, W_w, W_b,
                                       bn_g, bn_b, bn_m, bn_v,
                                       wt_theta, wt_phi, wt_g, wt_W, alpha, beta2);
  conv3_pool<<<576, 256, 0, stream>>>(x, wt_theta, wt_phi, wt_g,
                                      theta_b, phi_b, g_b, theta, phi, g_t);
  attn_fused<<<576, 512, 0, stream>>>(theta, phi, g_t, wt_W, alpha, beta2, x, out);
}

// Round 4
// 86.534 us; speedup vs baseline: 1.7354x; 1.7354x over previous
//
#include <hip/hip_runtime.h>
#include <hip/hip_bf16.h>

#define NB 4
#define NC 128
#define NH 96
#define NQ 9216
#define NKV 2304

typedef __bf16 bf8 __attribute__((ext_vector_type(8)));
typedef float f4 __attribute__((ext_vector_type(4)));
typedef unsigned short u16t;
typedef unsigned int u32t;
typedef u32t u32x2 __attribute__((ext_vector_type(2)));

static __device__ __forceinline__ u16t f2bf(float f){
  u32t u = __builtin_bit_cast(u32t, f);
  u = (u + 0x7fffu + ((u >> 16) & 1u)) >> 16;
  return (u16t)u;
}

static __device__ __forceinline__ f4 mfma16(bf8 a, bf8 b, f4 c){
  return __builtin_amdgcn_mfma_f32_16x16x32_bf16(a, b, c, 0, 0, 0);
}

// global -> LDS direct (16B per lane). dest: wave-uniform base + lane*16.
#define GLDS16(gp, lp) __builtin_amdgcn_global_load_lds( \
    (const u32t*)(gp), (u32t*)(lp), 16, 0, 0)

// ---------------------------------------------------------------------------
// Kernel 1: weights -> bf16, fold BN into alpha/beta2
// ---------------------------------------------------------------------------
__global__ __launch_bounds__(256) void prep_weights(
    const float* __restrict__ g_w, const float* __restrict__ theta_w,
    const float* __restrict__ phi_w, const float* __restrict__ W_w,
    const float* __restrict__ W_b, const float* __restrict__ bn_gamma,
    const float* __restrict__ bn_beta, const float* __restrict__ bn_mean,
    const float* __restrict__ bn_var,
    u16t* __restrict__ wt_theta, u16t* __restrict__ wt_phi,
    u16t* __restrict__ wt_g, u16t* __restrict__ wt_W,
    float* __restrict__ alpha, float* __restrict__ beta2)
{
  int i = blockIdx.x * 256 + threadIdx.x;
  wt_theta[i] = f2bf(theta_w[i]);
  wt_phi[i]   = f2bf(phi_w[i]);
  wt_g[i]     = f2bf(g_w[i]);
  wt_W[i]     = f2bf(W_w[i]);
  if (blockIdx.x == 0 && threadIdx.x < 128){
    int t = threadIdx.x;
    float inv = bn_gamma[t] * rsqrtf(bn_var[t] + 1e-5f);
    alpha[t] = inv;
    beta2[t] = W_b[t]*inv + bn_beta[t] - bn_mean[t]*inv;
  }
}

// ---------------------------------------------------------------------------
// Kernel 2: theta/phi/g 1x1 convs via MFMA + fused 2x2 maxpool for phi/g.
// theta stores now go through an LDS transpose -> coalesced b128 stores.
// ---------------------------------------------------------------------------
__global__ __launch_bounds__(256) void conv3_pool(
    const float* __restrict__ x,
    const u16t* __restrict__ wt_theta, const u16t* __restrict__ wt_phi,
    const u16t* __restrict__ wt_g,
    const float* __restrict__ theta_b, const float* __restrict__ phi_b,
    const float* __restrict__ g_b,
    u16t* __restrict__ theta, u16t* __restrict__ phi, u16t* __restrict__ g_t)
{
  __shared__ __align__(16) u16t xt[64][136];   // [linear pixel][c]; reused as th_lds
  const int blk = blockIdx.x;
  const int batch = blk / 144;
  const int t144 = blk % 144;
  const int ph = t144 / 3;
  const int pw0 = (t144 % 3) * 16;
  const int t = threadIdx.x;
  const float* xb = x + (size_t)batch * NC * NQ;

  #pragma unroll
  for (int i = 0; i < 32; ++i){
    int idx = i*256 + t;
    int c = idx >> 6;
    int pl = idx & 63;                         // linear: (row<<5)|col
    int q = (ph*2 + (pl>>5))*NH + pw0*2 + (pl & 31);
    xt[pl][c] = f2bf(xb[(size_t)c*NQ + q]);
  }
  __syncthreads();

  const int w = t >> 6, l = t & 63, lm = l & 15, lg = l >> 4;
  auto PL = [](int pxi){
    return (((pxi>>1)&1) << 5) + 8*(pxi>>4) + 2*((pxi>>2)&3) + (pxi&1);
  };
  auto QROW = [&](int pxi){
    return (ph*2 + ((pxi>>1)&1))*NH + (pw0 + 4*(pxi>>4) + ((pxi>>2)&3))*2 + (pxi&1);
  };
  bf8 a[4];
  #pragma unroll
  for (int k = 0; k < 4; ++k)
    a[k] = *(const bf8*)&xt[PL(w*16 + lm)][k*32 + lg*8];

  const int kv = ph*48 + pw0 + 4*w + lg;

  // theta conv -> regs
  f4 Dth[4];
  #pragma unroll
  for (int s = 0; s < 4; ++s){
    float bv = theta_b[s*16 + lm];
    f4 D = {bv, bv, bv, bv};
    #pragma unroll
    for (int k = 0; k < 4; ++k){
      bf8 b = *(const bf8*)&wt_theta[(s*16 + lm)*128 + k*32 + lg*8];
      D = mfma16(a[k], b, D);
    }
    Dth[s] = D;
  }
  { // phi (pooled) - direct store (lm-contiguous, cheap)
    u16t* pp = phi + (size_t)batch * NKV * 64;
    #pragma unroll
    for (int s = 0; s < 4; ++s){
      float bv = phi_b[s*16 + lm];
      f4 D = {bv, bv, bv, bv};
      #pragma unroll
      for (int k = 0; k < 4; ++k){
        bf8 b = *(const bf8*)&wt_phi[(s*16 + lm)*128 + k*32 + lg*8];
        D = mfma16(a[k], b, D);
      }
      float mx = fmaxf(fmaxf(D[0], D[1]), fmaxf(D[2], D[3]));
      pp[(size_t)kv*64 + s*16 + lm] = f2bf(mx);
    }
  }
  { // g (pooled, transposed store)
    u16t* gt = g_t + (size_t)batch * 64 * NKV;
    #pragma unroll
    for (int s = 0; s < 4; ++s){
      float bv = g_b[s*16 + lm];
      f4 D = {bv, bv, bv, bv};
      #pragma unroll
      for (int k = 0; k < 4; ++k){
        bf8 b = *(const bf8*)&wt_g[(s*16 + lm)*128 + k*32 + lg*8];
        D = mfma16(a[k], b, D);
      }
      float mx = fmaxf(fmaxf(D[0], D[1]), fmaxf(D[2], D[3]));
      gt[(size_t)(s*16 + lm)*NKV + kv] = f2bf(mx);
    }
  }

  // theta: bounce through LDS, store coalesced b128 rows
  __syncthreads();                     // xt frag reads done everywhere
  u16t* tl = &xt[0][0];                // reuse as [64][72]
  #pragma unroll
  for (int s = 0; s < 4; ++s)
    #pragma unroll
    for (int r = 0; r < 4; ++r)
      tl[(w*16 + lg*4 + r)*72 + s*16 + lm] = f2bf(Dth[s][r]);
  __syncthreads();
  {
    u16t* th = theta + (size_t)batch * NQ * 64;
    #pragma unroll
    for (int p = 0; p < 2; ++p){
      int slot = t + 256*p;            // 512 slots = 64 rows x 8 pieces
      int row = slot >> 3, piece = slot & 7;
      int q = QROW(row);
      *(bf8*)&th[(size_t)q*64 + piece*8] = *(const bf8*)&tl[row*72 + piece*8];
    }
  }
}

// ---------------------------------------------------------------------------
// Kernel 3: fused attention + W-conv + BN + residual.
// 256 blocks (1/CU), 384 threads = 6 waves = 3 q-tiles(48q, M_rep=3) x 2 kh.
// phi/g tiles LDS-staged via global_load_lds (pre-swizzled source, T2 XOR
// swizzle on ds_read), double-buffered, 2-phase schedule.
// ---------------------------------------------------------------------------
__global__ __launch_bounds__(384) void attn_fused(
    const u16t* __restrict__ theta, const u16t* __restrict__ phi,
    const u16t* __restrict__ g_t, const u16t* __restrict__ wt_W,
    const float* __restrict__ alpha, const float* __restrict__ beta2,
    const float* __restrict__ x, float* __restrict__ out)
{
  // region map:
  //  loop:    [0,32768) phi stage [kh][dbuf][8KB]; [32768,65536) g stage;
  //           [65536,107008) P per wave [48][72] u16
  //  epi:     yp f32 [144][68] @0 ; y_lds u16 [144][72] @75264 ;
  //           out_lds f32 [144][130] @0
  __shared__ __align__(16) char SM[107008];
  __shared__ float sums[2][144];

  const int bid = blockIdx.x;
  const int blk = (bid & 7)*32 + (bid >> 3);   // XCD chunk swizzle (256=8x32)
  const int batch = blk >> 6;
  const int qb = (blk & 63) * 144;
  const int t = threadIdx.x;
  const int w = t >> 6, l = t & 63, lm = l & 15, lg = l >> 4;
  const int qw = w >> 1, kh = w & 1;

  // theta B-frags (queries qb + qw*48 .. +47)
  const u16t* th = theta + ((size_t)batch*NQ + qb)*64;
  bf8 a[3][2];
  #pragma unroll
  for (int mr = 0; mr < 3; ++mr){
    a[mr][0] = *(const bf8*)&th[(qw*48 + mr*16 + lm)*64 + lg*8];
    a[mr][1] = *(const bf8*)&th[(qw*48 + mr*16 + lm)*64 + 32 + lg*8];
  }

  const char* phc = (const char*)(phi + (size_t)batch*NKV*64);
  const char* gtc = (const char*)(g_t + (size_t)batch*64*NKV);

  // stage one step: tiles (kh2*18 + kt_s) for kh2=0,1; phi+g; 32 units of 1KB
  auto STAGE = [&](int kt_s, int buf){
    #pragma unroll
    for (int j = 0; j < 6; ++j){
      int u = w + 6*j;
      if (u < 32){
        int khu = u >> 4, isg = (u >> 3) & 1, sub = u & 7;
        int row = sub*8 + (l >> 3);
        int swz = ((l & 7) ^ (l >> 3)) << 4;
        int kb = (khu*18 + kt_s) * 64;
        char* dst = SM + (isg ? 32768 : 0) + (khu*2 + buf)*8192 + sub*1024 + l*16;
        const char* src = isg
          ? gtc + (size_t)row*(NKV*2) + (size_t)kb*2 + swz
          : phc + (size_t)(kb + row)*128 + swz;
        GLDS16(src, dst);
      }
    }
  };

  f4 Y[3][4];
  #pragma unroll
  for (int mr = 0; mr < 3; ++mr)
    #pragma unroll
    for (int s = 0; s < 4; ++s)
      Y[mr][s] = f4{0.f, 0.f, 0.f, 0.f};
  float lsum[3] = {0.f, 0.f, 0.f};

  u16t* Prow = (u16t*)(SM + 65536 + w*6912);   // [48][72] u16, per-wave

  STAGE(0, 0);
  asm volatile("s_waitcnt vmcnt(0)" ::: "memory");
  __syncthreads();

  #pragma unroll 2
  for (int kt = 0; kt < 18; ++kt){
    const int buf = kt & 1;
    if (kt + 1 < 18) STAGE(kt + 1, buf ^ 1);
    const char* pb = SM + (kh*2 + buf)*8192;
    const char* gb = SM + 32768 + (kh*2 + buf)*8192;

    // phi frags (swizzled read)
    bf8 bp[4][2];
    #pragma unroll
    for (int tt = 0; tt < 4; ++tt){
      int rb = (tt*16 + lm)*128;
      int m7 = lm & 7;
      bp[tt][0] = *(const bf8*)(pb + rb + ((lg ^ m7) << 4));
      bp[tt][1] = *(const bf8*)(pb + rb + (((4 + lg) ^ m7) << 4));
    }
    // g frags (issue early, independent)
    bf8 bg[4][2];
    #pragma unroll
    for (int s = 0; s < 4; ++s){
      int rb = (s*16 + lm)*128;
      int m7 = lm & 7;
      bg[s][0] = *(const bf8*)(gb + rb + ((lg ^ m7) << 4));
      bg[s][1] = *(const bf8*)(gb + rb + (((4 + lg) ^ m7) << 4));
    }
    // swapped QK: D[key rows][query cols]; lane lm = query
    f4 S[3][4];
    #pragma unroll
    for (int tt = 0; tt < 4; ++tt)
      #pragma unroll
      for (int mr = 0; mr < 3; ++mr){
        f4 z = {0.f, 0.f, 0.f, 0.f};
        z = mfma16(bp[tt][0], a[mr][0], z);
        S[mr][tt] = mfma16(bp[tt][1], a[mr][1], z);
      }
    // P = exp(S-30) = 2^(S*log2e - 30*log2e); pack via cvt_pk; b64 P writes
    #pragma unroll
    for (int mr = 0; mr < 3; ++mr)
      #pragma unroll
      for (int tt = 0; tt < 4; ++tt){
        float p0, p1, p2, p3;
        float a0 = fmaf(S[mr][tt][0], 1.44269504f, -43.2808512f);
        float a1 = fmaf(S[mr][tt][1], 1.44269504f, -43.2808512f);
        float a2 = fmaf(S[mr][tt][2], 1.44269504f, -43.2808512f);
        float a3 = fmaf(S[mr][tt][3], 1.44269504f, -43.2808512f);
        asm("v_exp_f32 %0, %1" : "=v"(p0) : "v"(a0));
        asm("v_exp_f32 %0, %1" : "=v"(p1) : "v"(a1));
        asm("v_exp_f32 %0, %1" : "=v"(p2) : "v"(a2));
        asm("v_exp_f32 %0, %1" : "=v"(p3) : "v"(a3));
        lsum[mr] += (p0 + p1) + (p2 + p3);
        u32t lo, hi;
        asm("v_cvt_pk_bf16_f32 %0, %1, %2" : "=v"(lo) : "v"(p0), "v"(p1));
        asm("v_cvt_pk_bf16_f32 %0, %1, %2" : "=v"(hi) : "v"(p2), "v"(p3));
        *(u32x2*)&Prow[(mr*16 + lm)*72 + tt*16 + lg*4] = u32x2{lo, hi};
      }
    // PV
    #pragma unroll
    for (int mr = 0; mr < 3; ++mr){
      bf8 pa0 = *(const bf8*)&Prow[(mr*16 + lm)*72 + lg*8];
      bf8 pa1 = *(const bf8*)&Prow[(mr*16 + lm)*72 + 32 + lg*8];
      #pragma unroll
      for (int s = 0; s < 4; ++s){
        Y[mr][s] = mfma16(pa0, bg[s][0], Y[mr][s]);
        Y[mr][s] = mfma16(pa1, bg[s][1], Y[mr][s]);
      }
    }
    asm volatile("s_waitcnt vmcnt(0)" ::: "memory");
    __syncthreads();
  }

  // per-query sums (reduce over lg groups)
  #pragma unroll
  for (int mr = 0; mr < 3; ++mr){
    float sv = lsum[mr];
    sv += __shfl_xor(sv, 16);
    sv += __shfl_xor(sv, 32);
    if (lg == 0) sums[kh][qw*48 + mr*16 + lm] = sv;
  }

  // combine kh halves in yp f32 [144][68]
  float (*yp)[68] = (float (*)[68])SM;
  if (kh == 0){
    #pragma unroll
    for (int mr = 0; mr < 3; ++mr)
      #pragma unroll
      for (int s = 0; s < 4; ++s)
        #pragma unroll
        for (int r = 0; r < 4; ++r)
          yp[qw*48 + mr*16 + lg*4 + r][s*16 + lm] = Y[mr][s][r];
  }
  __syncthreads();
  if (kh == 1){
    #pragma unroll
    for (int mr = 0; mr < 3; ++mr)
      #pragma unroll
      for (int s = 0; s < 4; ++s)
        #pragma unroll
        for (int r = 0; r < 4; ++r)
          yp[qw*48 + mr*16 + lg*4 + r][s*16 + lm] += Y[mr][s][r];
  }
  __syncthreads();

  // normalize -> bf16 y_lds [144][72]
  u16t* yl = (u16t*)(SM + 75264);
  #pragma unroll
  for (int i = 0; i < 12; ++i){
    int p = t + 384*i;            // 4608 pairs = 144q x 32
    int q = p >> 5, cp = p & 31;
    float tot = sums[0][q] + sums[1][q];
    float inv = 1.0f / tot;
    float v0 = yp[q][cp*2] * inv;
    float v1 = yp[q][cp*2 + 1] * inv;
    u32t pk;
    asm("v_cvt_pk_bf16_f32 %0, %1, %2" : "=v"(pk) : "v"(v0), "v"(v1));
    *(u32t*)&yl[q*72 + cp*2] = pk;
  }
  __syncthreads();

  // W conv: 72 tiles (9 qt x 8 ct) over 6 waves
  float (*ol)[130] = (float (*)[130])SM;
  #pragma unroll
  for (int i = 0; i < 12; ++i){
    int tau = w + 6*i;            // 0..71
    int qt = tau >> 3, ct = tau & 7;
    bf8 ya0 = *(const bf8*)&yl[(qt*16 + lm)*72 + lg*8];
    bf8 ya1 = *(const bf8*)&yl[(qt*16 + lm)*72 + 32 + lg*8];
    const u16t* wr = wt_W + (ct*16 + lm)*64;
    bf8 b0 = *(const bf8*)&wr[lg*8];
    bf8 b1 = *(const bf8*)&wr[lg*8 + 32];
    f4 z = {0.f, 0.f, 0.f, 0.f};
    z = mfma16(ya0, b0, z);
    z = mfma16(ya1, b1, z);
    #pragma unroll
    for (int r = 0; r < 4; ++r)
      ol[qt*16 + lg*4 + r][ct*16 + lm] = z[r];
  }
  __syncthreads();

  // BN + residual; float4 stores (144q = 36 float4 per channel)
  const float* xb = x + (size_t)batch*NC*NQ + qb;
  float* ob = out + (size_t)batch*NC*NQ + qb;
  #pragma unroll
  for (int i = 0; i < 12; ++i){
    int idx = t + 384*i;          // < 4608 = 128c x 36
    int c = idx / 36, qv = idx % 36;
    float4 xv = *(const float4*)&xb[(size_t)c*NQ + qv*4];
    float al = alpha[c], be = beta2[c];
    float4 ov;
    ov.x = ol[qv*4 + 0][c]*al + be + xv.x;
    ov.y = ol[qv*4 + 1][c]*al + be + xv.y;
    ov.z = ol[qv*4 + 2][c]*al + be + xv.z;
    ov.w = ol[qv*4 + 3][c]*al + be + xv.w;
    *(float4*)&ob[(size_t)c*NQ + qv*4] = ov;
  }
}

// ---------------------------------------------------------------------------
extern "C" void kernel_launch(void* const* d_in, const int* in_sizes, int n_in,
                              void* d_out, int out_size, void* d_ws, size_t ws_size,
                              hipStream_t stream)
{
  const float* x       = (const float*)d_in[0];
  const float* g_w     = (const float*)d_in[1];
  const float* g_b     = (const float*)d_in[2];
  const float* theta_w = (const float*)d_in[3];
  const float* theta_b = (const float*)d_in[4];
  const float* phi_w   = (const float*)d_in[5];
  const float* phi_b   = (const float*)d_in[6];
  const float* W_w     = (const float*)d_in[7];
  const float* W_b     = (const float*)d_in[8];
  const float* bn_g    = (const float*)d_in[9];
  const float* bn_b    = (const float*)d_in[10];
  const float* bn_m    = (const float*)d_in[11];
  const float* bn_v    = (const float*)d_in[12];
  float* out = (float*)d_out;

  char* ws = (char*)d_ws;
  size_t off = 0;
  u16t* theta = (u16t*)(ws + off); off += (size_t)NB*NQ*64*2;
  u16t* phi   = (u16t*)(ws + off); off += (size_t)NB*NKV*64*2;
  u16t* g_t   = (u16t*)(ws + off); off += (size_t)NB*64*NKV*2;
  u16t* wt_theta = (u16t*)(ws + off); off += 64*128*2;
  u16t* wt_phi   = (u16t*)(ws + off); off += 64*128*2;
  u16t* wt_g     = (u16t*)(ws + off); off += 64*128*2;
  u16t* wt_W     = (u16t*)(ws + off); off += 128*64*2;
  float* alpha = (float*)(ws + off); off += 128*4;
  float* beta2 = (float*)(ws + off); off += 128*4;
  if (off > ws_size) return;

  prep_weights<<<32, 256, 0, stream>>>(g_w, theta_w, phi_w, W_w, W_b,
                                       bn_g, bn_b, bn_m, bn_v,
                                       wt_theta, wt_phi, wt_g, wt_W, alpha, beta2);
  conv3_pool<<<576, 256, 0, stream>>>(x, wt_theta, wt_phi, wt_g,
                                      theta_b, phi_b, g_b, theta, phi, g_t);
  attn_fused<<<256, 384, 0, stream>>>(theta, phi, g_t, wt_W, alpha, beta2, x, out);
}

// Round 5
// 81.025 us; speedup vs baseline: 1.8534x; 1.0680x over previous
//
#include <hip/hip_runtime.h>
#include <hip/hip_bf16.h>

#define NB 4
#define NC 128
#define NH 96
#define NQ 9216
#define NKV 2304

typedef __bf16 bf8 __attribute__((ext_vector_type(8)));
typedef float f4 __attribute__((ext_vector_type(4)));
typedef unsigned short u16t;
typedef unsigned int u32t;
typedef u32t u32x2 __attribute__((ext_vector_type(2)));

static __device__ __forceinline__ u16t f2bf(float f){
  u32t u = __builtin_bit_cast(u32t, f);
  u = (u + 0x7fffu + ((u >> 16) & 1u)) >> 16;
  return (u16t)u;
}

static __device__ __forceinline__ f4 mfma16(bf8 a, bf8 b, f4 c){
  return __builtin_amdgcn_mfma_f32_16x16x32_bf16(a, b, c, 0, 0, 0);
}

// global -> LDS direct (16B per lane). dest: wave-uniform base + lane*16.
#define GLDS16(gp, lp) __builtin_amdgcn_global_load_lds( \
    (const u32t*)(gp), (u32t*)(lp), 16, 0, 0)

// ---------------------------------------------------------------------------
// Kernel 1: weights -> bf16, fold BN into alpha/beta2
// ---------------------------------------------------------------------------
__global__ __launch_bounds__(256) void prep_weights(
    const float* __restrict__ g_w, const float* __restrict__ theta_w,
    const float* __restrict__ phi_w, const float* __restrict__ W_w,
    const float* __restrict__ W_b, const float* __restrict__ bn_gamma,
    const float* __restrict__ bn_beta, const float* __restrict__ bn_mean,
    const float* __restrict__ bn_var,
    u16t* __restrict__ wt_theta, u16t* __restrict__ wt_phi,
    u16t* __restrict__ wt_g, u16t* __restrict__ wt_W,
    float* __restrict__ alpha, float* __restrict__ beta2)
{
  int i = blockIdx.x * 256 + threadIdx.x;
  wt_theta[i] = f2bf(theta_w[i]);
  wt_phi[i]   = f2bf(phi_w[i]);
  wt_g[i]     = f2bf(g_w[i]);
  wt_W[i]     = f2bf(W_w[i]);
  if (blockIdx.x == 0 && threadIdx.x < 128){
    int t = threadIdx.x;
    float inv = bn_gamma[t] * rsqrtf(bn_var[t] + 1e-5f);
    alpha[t] = inv;
    beta2[t] = W_b[t]*inv + bn_beta[t] - bn_mean[t]*inv;
  }
}

// ---------------------------------------------------------------------------
// Kernel 2: theta/phi/g 1x1 convs via MFMA + fused 2x2 maxpool for phi/g.
// x loaded as float4 (coalesced 128B segments); pool permutation on LDS read.
// ---------------------------------------------------------------------------
__global__ __launch_bounds__(256) void conv3_pool(
    const float* __restrict__ x,
    const u16t* __restrict__ wt_theta, const u16t* __restrict__ wt_phi,
    const u16t* __restrict__ wt_g,
    const float* __restrict__ theta_b, const float* __restrict__ phi_b,
    const float* __restrict__ g_b,
    u16t* __restrict__ theta, u16t* __restrict__ phi, u16t* __restrict__ g_t)
{
  __shared__ __align__(16) u16t xt[64][136];   // [linear pixel][c]; reused as th_lds
  const int blk = blockIdx.x;
  const int batch = blk / 144;
  const int t144 = blk % 144;
  const int ph = t144 / 3;
  const int pw0 = (t144 % 3) * 16;
  const int t = threadIdx.x;
  const float* xb = x + (size_t)batch * NC * NQ;

  #pragma unroll
  for (int i = 0; i < 8; ++i){
    int slot = i*256 + t;            // 2048 = 128c x 16 px-quads
    int c = slot >> 4;
    int quad = slot & 15;
    int row = quad >> 3, col4 = (quad & 7)*4;
    int q = (ph*2 + row)*NH + pw0*2 + col4;
    float4 v = *(const float4*)&xb[(size_t)c*NQ + q];
    int pl = row*32 + col4;
    xt[pl+0][c] = f2bf(v.x);
    xt[pl+1][c] = f2bf(v.y);
    xt[pl+2][c] = f2bf(v.z);
    xt[pl+3][c] = f2bf(v.w);
  }
  __syncthreads();

  const int w = t >> 6, l = t & 63, lm = l & 15, lg = l >> 4;
  auto PL = [](int pxi){
    return (((pxi>>1)&1) << 5) + 8*(pxi>>4) + 2*((pxi>>2)&3) + (pxi&1);
  };
  auto QROW = [&](int pxi){
    return (ph*2 + ((pxi>>1)&1))*NH + (pw0 + 4*(pxi>>4) + ((pxi>>2)&3))*2 + (pxi&1);
  };
  bf8 a[4];
  #pragma unroll
  for (int k = 0; k < 4; ++k)
    a[k] = *(const bf8*)&xt[PL(w*16 + lm)][k*32 + lg*8];

  const int kv = ph*48 + pw0 + 4*w + lg;

  // theta conv -> regs
  f4 Dth[4];
  #pragma unroll
  for (int s = 0; s < 4; ++s){
    float bv = theta_b[s*16 + lm];
    f4 D = {bv, bv, bv, bv};
    #pragma unroll
    for (int k = 0; k < 4; ++k){
      bf8 b = *(const bf8*)&wt_theta[(s*16 + lm)*128 + k*32 + lg*8];
      D = mfma16(a[k], b, D);
    }
    Dth[s] = D;
  }
  { // phi (pooled)
    u16t* pp = phi + (size_t)batch * NKV * 64;
    #pragma unroll
    for (int s = 0; s < 4; ++s){
      float bv = phi_b[s*16 + lm];
      f4 D = {bv, bv, bv, bv};
      #pragma unroll
      for (int k = 0; k < 4; ++k){
        bf8 b = *(const bf8*)&wt_phi[(s*16 + lm)*128 + k*32 + lg*8];
        D = mfma16(a[k], b, D);
      }
      float mx = fmaxf(fmaxf(D[0], D[1]), fmaxf(D[2], D[3]));
      pp[(size_t)kv*64 + s*16 + lm] = f2bf(mx);
    }
  }
  { // g (pooled, transposed store)
    u16t* gt = g_t + (size_t)batch * 64 * NKV;
    #pragma unroll
    for (int s = 0; s < 4; ++s){
      float bv = g_b[s*16 + lm];
      f4 D = {bv, bv, bv, bv};
      #pragma unroll
      for (int k = 0; k < 4; ++k){
        bf8 b = *(const bf8*)&wt_g[(s*16 + lm)*128 + k*32 + lg*8];
        D = mfma16(a[k], b, D);
      }
      float mx = fmaxf(fmaxf(D[0], D[1]), fmaxf(D[2], D[3]));
      gt[(size_t)(s*16 + lm)*NKV + kv] = f2bf(mx);
    }
  }

  // theta: bounce through LDS, store coalesced b128 rows
  __syncthreads();
  u16t* tl = &xt[0][0];                // reuse as [64][72]
  #pragma unroll
  for (int s = 0; s < 4; ++s)
    #pragma unroll
    for (int r = 0; r < 4; ++r)
      tl[(w*16 + lg*4 + r)*72 + s*16 + lm] = f2bf(Dth[s][r]);
  __syncthreads();
  {
    u16t* th = theta + (size_t)batch * NQ * 64;
    #pragma unroll
    for (int p = 0; p < 2; ++p){
      int slot = t + 256*p;            // 512 slots = 64 rows x 8 pieces
      int row = slot >> 3, piece = slot & 7;
      int q = QROW(row);
      *(bf8*)&th[(size_t)q*64 + piece*8] = *(const bf8*)&tl[row*72 + piece*8];
    }
  }
}

// ---------------------------------------------------------------------------
// Kernel 3: fused attention + W-conv + BN + residual.
// 256 blocks (1/CU), 384 threads = 6 waves = 3 q-tiles(48q, M_rep=3) x 2 kh.
// Triple-buffered global_load_lds staging with counted vmcnt (T3+T4): loads
// stay in flight across raw s_barriers; never drains in steady state.
// ---------------------------------------------------------------------------
#define PHI_OFF 0
#define G_OFF   49152
#define P_OFF   98304
#define SCRAP_OFF 139776

__global__ __launch_bounds__(384) void attn_fused(
    const u16t* __restrict__ theta, const u16t* __restrict__ phi,
    const u16t* __restrict__ g_t, const u16t* __restrict__ wt_W,
    const float* __restrict__ alpha, const float* __restrict__ beta2,
    const float* __restrict__ x, float* __restrict__ out)
{
  // loop:  [0,49152) phi [kh][3buf][8KB]; [49152,98304) g [kh][3buf][8KB];
  //        [98304,139776) P per wave [48][72] u16; [139776,143872) scrap
  // epi:   yp f32 [144][68] @0 ; y_lds u16 [144][72] @98304 ;
  //        out_lds f32 [144][130] @0
  __shared__ __align__(16) char SM[143872];
  __shared__ float sums[2][144];

  const int bid = blockIdx.x;
  const int blk = (bid & 7)*32 + (bid >> 3);   // XCD chunk swizzle (256=8x32)
  const int batch = blk >> 6;
  const int qb = (blk & 63) * 144;
  const int t = threadIdx.x;
  const int w = t >> 6, l = t & 63, lm = l & 15, lg = l >> 4;
  const int qw = w >> 1, kh = w & 1;

  // theta B-frags (queries qb + qw*48 .. +47)
  const u16t* th = theta + ((size_t)batch*NQ + qb)*64;
  bf8 a[3][2];
  #pragma unroll
  for (int mr = 0; mr < 3; ++mr){
    a[mr][0] = *(const bf8*)&th[(qw*48 + mr*16 + lm)*64 + lg*8];
    a[mr][1] = *(const bf8*)&th[(qw*48 + mr*16 + lm)*64 + 32 + lg*8];
  }
  // resolve theta loads now so the compiler's auto-wait stays out of the loop
  asm volatile("s_waitcnt vmcnt(0)" ::: "memory");

  const char* phc = (const char*)(phi + (size_t)batch*NKV*64);
  const char* gtc = (const char*)(g_t + (size_t)batch*64*NKV);

  // stage one kt step into buffer bufc: 36 units of 1KB, 6 per wave (4 dummy)
  auto STAGE = [&](int kt_s, int bufc){
    #pragma unroll
    for (int j = 0; j < 6; ++j){
      int u = w*6 + j;                 // wave-contiguous, uniform 6 per wave
      int ur = (u < 32) ? u : (u - 32);
      int khu = ur >> 4, isg = (ur >> 3) & 1, sub = ur & 7;
      int row = sub*8 + (l >> 3);
      int swz = ((l & 7) ^ (l >> 3)) << 4;
      int kb = (khu*18 + kt_s) * 64;
      char* dst = (u < 32)
        ? SM + (isg ? G_OFF : PHI_OFF) + (khu*3 + bufc)*8192 + sub*1024 + l*16
        : SM + SCRAP_OFF + (u - 32)*1024 + l*16;
      const char* src = isg
        ? gtc + (size_t)row*(NKV*2) + (size_t)kb*2 + swz
        : phc + (size_t)(kb + row)*128 + swz;
      GLDS16(src, dst);
    }
  };

  f4 Y[3][4];
  #pragma unroll
  for (int mr = 0; mr < 3; ++mr)
    #pragma unroll
    for (int s = 0; s < 4; ++s)
      Y[mr][s] = f4{0.f, 0.f, 0.f, 0.f};
  float lsum[3] = {0.f, 0.f, 0.f};

  u16t* Prow = (u16t*)(SM + P_OFF + w*6912);   // [48][72] u16, per-wave

  STAGE(0, 0);
  STAGE(1, 1);

  int bufc = 0;
  for (int kt = 0; kt < 18; ++kt){
    // barrier 1: everyone done with compute(kt-1); buffer (kt+2)%3 is free
    __builtin_amdgcn_s_barrier();
    if (kt < 16){
      STAGE(kt + 2, (bufc == 0) ? 2 : bufc - 1);
      asm volatile("s_waitcnt vmcnt(12)" ::: "memory");   // stage(kt) landed
    } else if (kt == 16){
      asm volatile("s_waitcnt vmcnt(6)" ::: "memory");
    } else {
      asm volatile("s_waitcnt vmcnt(0)" ::: "memory");
    }
    // barrier 2: ALL waves' stage(kt) landed
    __builtin_amdgcn_s_barrier();

    const char* pb = SM + PHI_OFF + (kh*3 + bufc)*8192;
    const char* gb = SM + G_OFF   + (kh*3 + bufc)*8192;

    // phi frags (swizzled read)
    bf8 bp[4][2];
    #pragma unroll
    for (int tt = 0; tt < 4; ++tt){
      int rb = (tt*16 + lm)*128;
      int m7 = lm & 7;
      bp[tt][0] = *(const bf8*)(pb + rb + ((lg ^ m7) << 4));
      bp[tt][1] = *(const bf8*)(pb + rb + (((4 + lg) ^ m7) << 4));
    }
    // g frags
    bf8 bg[4][2];
    #pragma unroll
    for (int s = 0; s < 4; ++s){
      int rb = (s*16 + lm)*128;
      int m7 = lm & 7;
      bg[s][0] = *(const bf8*)(gb + rb + ((lg ^ m7) << 4));
      bg[s][1] = *(const bf8*)(gb + rb + (((4 + lg) ^ m7) << 4));
    }
    // swapped QK: D[key rows][query cols]; lane lm = query
    f4 S[3][4];
    __builtin_amdgcn_s_setprio(1);
    #pragma unroll
    for (int tt = 0; tt < 4; ++tt)
      #pragma unroll
      for (int mr = 0; mr < 3; ++mr){
        f4 z = {0.f, 0.f, 0.f, 0.f};
        z = mfma16(bp[tt][0], a[mr][0], z);
        S[mr][tt] = mfma16(bp[tt][1], a[mr][1], z);
      }
    __builtin_amdgcn_s_setprio(0);
    // P = exp(S-30) via 2^(S*log2e - 43.28...); cvt_pk pack; b64 P writes
    #pragma unroll
    for (int mr = 0; mr < 3; ++mr)
      #pragma unroll
      for (int tt = 0; tt < 4; ++tt){
        float p0, p1, p2, p3;
        float a0 = fmaf(S[mr][tt][0], 1.44269504f, -43.2808512f);
        float a1 = fmaf(S[mr][tt][1], 1.44269504f, -43.2808512f);
        float a2 = fmaf(S[mr][tt][2], 1.44269504f, -43.2808512f);
        float a3 = fmaf(S[mr][tt][3], 1.44269504f, -43.2808512f);
        asm("v_exp_f32 %0, %1" : "=v"(p0) : "v"(a0));
        asm("v_exp_f32 %0, %1" : "=v"(p1) : "v"(a1));
        asm("v_exp_f32 %0, %1" : "=v"(p2) : "v"(a2));
        asm("v_exp_f32 %0, %1" : "=v"(p3) : "v"(a3));
        lsum[mr] += (p0 + p1) + (p2 + p3);
        u32t lo, hi;
        asm("v_cvt_pk_bf16_f32 %0, %1, %2" : "=v"(lo) : "v"(p0), "v"(p1));
        asm("v_cvt_pk_bf16_f32 %0, %1, %2" : "=v"(hi) : "v"(p2), "v"(p3));
        *(u32x2*)&Prow[(mr*16 + lm)*72 + tt*16 + lg*4] = u32x2{lo, hi};
      }
    // PV
    __builtin_amdgcn_s_setprio(1);
    #pragma unroll
    for (int mr = 0; mr < 3; ++mr){
      bf8 pa0 = *(const bf8*)&Prow[(mr*16 + lm)*72 + lg*8];
      bf8 pa1 = *(const bf8*)&Prow[(mr*16 + lm)*72 + 32 + lg*8];
      #pragma unroll
      for (int s = 0; s < 4; ++s){
        Y[mr][s] = mfma16(pa0, bg[s][0], Y[mr][s]);
        Y[mr][s] = mfma16(pa1, bg[s][1], Y[mr][s]);
      }
    }
    __builtin_amdgcn_s_setprio(0);
    bufc = (bufc == 2) ? 0 : bufc + 1;
  }

  // per-query sums (reduce over lg groups)
  #pragma unroll
  for (int mr = 0; mr < 3; ++mr){
    float sv = lsum[mr];
    sv += __shfl_xor(sv, 16);
    sv += __shfl_xor(sv, 32);
    if (lg == 0) sums[kh][qw*48 + mr*16 + lm] = sv;
  }

  __syncthreads();                       // stage region dead -> yp [144][68]
  float (*yp)[68] = (float (*)[68])SM;
  if (kh == 0){
    #pragma unroll
    for (int mr = 0; mr < 3; ++mr)
      #pragma unroll
      for (int s = 0; s < 4; ++s)
        #pragma unroll
        for (int r = 0; r < 4; ++r)
          yp[qw*48 + mr*16 + lg*4 + r][s*16 + lm] = Y[mr][s][r];
  }
  __syncthreads();
  if (kh == 1){
    #pragma unroll
    for (int mr = 0; mr < 3; ++mr)
      #pragma unroll
      for (int s = 0; s < 4; ++s)
        #pragma unroll
        for (int r = 0; r < 4; ++r)
          yp[qw*48 + mr*16 + lg*4 + r][s*16 + lm] += Y[mr][s][r];
  }
  __syncthreads();

  // normalize -> bf16 y_lds [144][72] (overlays dead P region)
  u16t* yl = (u16t*)(SM + P_OFF);
  #pragma unroll
  for (int i = 0; i < 12; ++i){
    int p = t + 384*i;            // 4608 pairs = 144q x 32
    int q = p >> 5, cp = p & 31;
    float tot = sums[0][q] + sums[1][q];
    float inv = 1.0f / tot;
    float v0 = yp[q][cp*2] * inv;
    float v1 = yp[q][cp*2 + 1] * inv;
    u32t pk;
    asm("v_cvt_pk_bf16_f32 %0, %1, %2" : "=v"(pk) : "v"(v0), "v"(v1));
    *(u32t*)&yl[q*72 + cp*2] = pk;
  }
  __syncthreads();

  // W conv: 72 tiles (9 qt x 8 ct) over 6 waves
  float (*ol)[130] = (float (*)[130])SM;
  #pragma unroll
  for (int i = 0; i < 12; ++i){
    int tau = w + 6*i;            // 0..71
    int qt = tau >> 3, ct = tau & 7;
    bf8 ya0 = *(const bf8*)&yl[(qt*16 + lm)*72 + lg*8];
    bf8 ya1 = *(const bf8*)&yl[(qt*16 + lm)*72 + 32 + lg*8];
    const u16t* wr = wt_W + (ct*16 + lm)*64;
    bf8 b0 = *(const bf8*)&wr[lg*8];
    bf8 b1 = *(const bf8*)&wr[lg*8 + 32];
    f4 z = {0.f, 0.f, 0.f, 0.f};
    z = mfma16(ya0, b0, z);
    z = mfma16(ya1, b1, z);
    #pragma unroll
    for (int r = 0; r < 4; ++r)
      ol[qt*16 + lg*4 + r][ct*16 + lm] = z[r];
  }
  __syncthreads();

  // BN + residual; float4 stores (144q = 36 float4 per channel)
  const float* xb = x + (size_t)batch*NC*NQ + qb;
  float* ob = out + (size_t)batch*NC*NQ + qb;
  #pragma unroll
  for (int i = 0; i < 12; ++i){
    int idx = t + 384*i;          // < 4608 = 128c x 36
    int c = idx / 36, qv = idx % 36;
    float4 xv = *(const float4*)&xb[(size_t)c*NQ + qv*4];
    float al = alpha[c], be = beta2[c];
    float4 ov;
    ov.x = ol[qv*4 + 0][c]*al + be + xv.x;
    ov.y = ol[qv*4 + 1][c]*al + be + xv.y;
    ov.z = ol[qv*4 + 2][c]*al + be + xv.z;
    ov.w = ol[qv*4 + 3][c]*al + be + xv.w;
    *(float4*)&ob[(size_t)c*NQ + qv*4] = ov;
  }
}

// ---------------------------------------------------------------------------
extern "C" void kernel_launch(void* const* d_in, const int* in_sizes, int n_in,
                              void* d_out, int out_size, void* d_ws, size_t ws_size,
                              hipStream_t stream)
{
  const float* x       = (const float*)d_in[0];
  const float* g_w     = (const float*)d_in[1];
  const float* g_b     = (const float*)d_in[2];
  const float* theta_w = (const float*)d_in[3];
  const float* theta_b = (const float*)d_in[4];
  const float* phi_w   = (const float*)d_in[5];
  const float* phi_b   = (const float*)d_in[6];
  const float* W_w     = (const float*)d_in[7];
  const float* W_b     = (const float*)d_in[8];
  const float* bn_g    = (const float*)d_in[9];
  const float* bn_b    = (const float*)d_in[10];
  const float* bn_m    = (const float*)d_in[11];
  const float* bn_v    = (const float*)d_in[12];
  float* out = (float*)d_out;

  char* ws = (char*)d_ws;
  size_t off = 0;
  u16t* theta = (u16t*)(ws + off); off += (size_t)NB*NQ*64*2;
  u16t* phi   = (u16t*)(ws + off); off += (size_t)NB*NKV*64*2;
  u16t* g_t   = (u16t*)(ws + off); off += (size_t)NB*64*NKV*2;
  u16t* wt_theta = (u16t*)(ws + off); off += 64*128*2;
  u16t* wt_phi   = (u16t*)(ws + off); off += 64*128*2;
  u16t* wt_g     = (u16t*)(ws + off); off += 64*128*2;
  u16t* wt_W     = (u16t*)(ws + off); off += 128*64*2;
  float* alpha = (float*)(ws + off); off += 128*4;
  float* beta2 = (float*)(ws + off); off += 128*4;
  if (off > ws_size) return;

  prep_weights<<<32, 256, 0, stream>>>(g_w, theta_w, phi_w, W_w, W_b,
                                       bn_g, bn_b, bn_m, bn_v,
                                       wt_theta, wt_phi, wt_g, wt_W, alpha, beta2);
  conv3_pool<<<576, 256, 0, stream>>>(x, wt_theta, wt_phi, wt_g,
                                      theta_b, phi_b, g_b, theta, phi, g_t);
  attn_fused<<<256, 384, 0, stream>>>(theta, phi, g_t, wt_W, alpha, beta2, x, out);
}

// Round 6
// 77.734 us; speedup vs baseline: 1.9319x; 1.0423x over previous
//
#include <hip/hip_runtime.h>
#include <hip/hip_bf16.h>

#define NB 4
#define NC 128
#define NH 96
#define NQ 9216
#define NKV 2304

typedef __bf16 bf8 __attribute__((ext_vector_type(8)));
typedef float f4 __attribute__((ext_vector_type(4)));
typedef unsigned short u16t;
typedef unsigned int u32t;
typedef u32t u32x4 __attribute__((ext_vector_type(4)));
typedef u16t u16x4v __attribute__((ext_vector_type(4)));

static __device__ __forceinline__ u16t f2bf(float f){
  u32t u = __builtin_bit_cast(u32t, f);
  u = (u + 0x7fffu + ((u >> 16) & 1u)) >> 16;
  return (u16t)u;
}

static __device__ __forceinline__ f4 mfma16(bf8 a, bf8 b, f4 c){
  return __builtin_amdgcn_mfma_f32_16x16x32_bf16(a, b, c, 0, 0, 0);
}

// global -> LDS direct (16B per lane). dest: wave-uniform base + lane*16.
#define GLDS16(gp, lp) __builtin_amdgcn_global_load_lds( \
    (const u32t*)(gp), (u32t*)(lp), 16, 0, 0)

// ---------------------------------------------------------------------------
// Kernel 1: weights -> bf16, fold BN into alpha/beta2
// ---------------------------------------------------------------------------
__global__ __launch_bounds__(256) void prep_weights(
    const float* __restrict__ g_w, const float* __restrict__ theta_w,
    const float* __restrict__ phi_w, const float* __restrict__ W_w,
    const float* __restrict__ W_b, const float* __restrict__ bn_gamma,
    const float* __restrict__ bn_beta, const float* __restrict__ bn_mean,
    const float* __restrict__ bn_var,
    u16t* __restrict__ wt_theta, u16t* __restrict__ wt_phi,
    u16t* __restrict__ wt_g, u16t* __restrict__ wt_W,
    float* __restrict__ alpha, float* __restrict__ beta2)
{
  int i = blockIdx.x * 256 + threadIdx.x;
  wt_theta[i] = f2bf(theta_w[i]);
  wt_phi[i]   = f2bf(phi_w[i]);
  wt_g[i]     = f2bf(g_w[i]);
  wt_W[i]     = f2bf(W_w[i]);
  if (blockIdx.x == 0 && threadIdx.x < 128){
    int t = threadIdx.x;
    float inv = bn_gamma[t] * rsqrtf(bn_var[t] + 1e-5f);
    alpha[t] = inv;
    beta2[t] = W_b[t]*inv + bn_beta[t] - bn_mean[t]*inv;
  }
}

// ---------------------------------------------------------------------------
// Kernel 2: theta/phi/g 1x1 convs via MFMA + fused 2x2 maxpool for phi/g.
// g_t stored in sigma-PERMUTED key order (within each 64-key MFMA tile):
//   key K = T*16 + L*4 + u  ->  pos (T>>1)*32 + L*8 + (T&1)*4 + u
// so attn's PV B-frag b128 reads match the register-resident P k-slots.
// g bounced through LDS -> 8B chunk stores (was 2B scatters).
// ---------------------------------------------------------------------------
__global__ __launch_bounds__(256) void conv3_pool(
    const float* __restrict__ x,
    const u16t* __restrict__ wt_theta, const u16t* __restrict__ wt_phi,
    const u16t* __restrict__ wt_g,
    const float* __restrict__ theta_b, const float* __restrict__ phi_b,
    const float* __restrict__ g_b,
    u16t* __restrict__ theta, u16t* __restrict__ phi, u16t* __restrict__ g_t)
{
  __shared__ __align__(16) u16t xt[64][136];   // [linear pixel][c]; reused
  const int blk = blockIdx.x;
  const int batch = blk / 144;
  const int t144 = blk % 144;
  const int ph = t144 / 3;
  const int pw0 = (t144 % 3) * 16;
  const int t = threadIdx.x;
  const float* xb = x + (size_t)batch * NC * NQ;

  #pragma unroll
  for (int i = 0; i < 8; ++i){
    int slot = i*256 + t;            // 2048 = 128c x 16 px-quads
    int c = slot >> 4;
    int quad = slot & 15;
    int row = quad >> 3, col4 = (quad & 7)*4;
    int q = (ph*2 + row)*NH + pw0*2 + col4;
    float4 v = *(const float4*)&xb[(size_t)c*NQ + q];
    int pl = row*32 + col4;
    xt[pl+0][c] = f2bf(v.x);
    xt[pl+1][c] = f2bf(v.y);
    xt[pl+2][c] = f2bf(v.z);
    xt[pl+3][c] = f2bf(v.w);
  }
  __syncthreads();

  const int w = t >> 6, l = t & 63, lm = l & 15, lg = l >> 4;
  auto PL = [](int pxi){
    return (((pxi>>1)&1) << 5) + 8*(pxi>>4) + 2*((pxi>>2)&3) + (pxi&1);
  };
  auto QROW = [&](int pxi){
    return (ph*2 + ((pxi>>1)&1))*NH + (pw0 + 4*(pxi>>4) + ((pxi>>2)&3))*2 + (pxi&1);
  };
  bf8 a[4];
  #pragma unroll
  for (int k = 0; k < 4; ++k)
    a[k] = *(const bf8*)&xt[PL(w*16 + lm)][k*32 + lg*8];

  const int kvbase = ph*48 + pw0;            // 16-aligned
  const int kv = kvbase + 4*w + lg;

  // theta conv -> regs
  f4 Dth[4];
  #pragma unroll
  for (int s = 0; s < 4; ++s){
    float bv = theta_b[s*16 + lm];
    f4 D = {bv, bv, bv, bv};
    #pragma unroll
    for (int k = 0; k < 4; ++k){
      bf8 b = *(const bf8*)&wt_theta[(s*16 + lm)*128 + k*32 + lg*8];
      D = mfma16(a[k], b, D);
    }
    Dth[s] = D;
  }
  { // phi (pooled) - direct store (lm-contiguous 32B segments)
    u16t* pp = phi + (size_t)batch * NKV * 64;
    #pragma unroll
    for (int s = 0; s < 4; ++s){
      float bv = phi_b[s*16 + lm];
      f4 D = {bv, bv, bv, bv};
      #pragma unroll
      for (int k = 0; k < 4; ++k){
        bf8 b = *(const bf8*)&wt_phi[(s*16 + lm)*128 + k*32 + lg*8];
        D = mfma16(a[k], b, D);
      }
      float mx = fmaxf(fmaxf(D[0], D[1]), fmaxf(D[2], D[3]));
      pp[(size_t)kv*64 + s*16 + lm] = f2bf(mx);
    }
  }
  // g (pooled) -> regs
  float gmx[4];
  #pragma unroll
  for (int s = 0; s < 4; ++s){
    float bv = g_b[s*16 + lm];
    f4 D = {bv, bv, bv, bv};
    #pragma unroll
    for (int k = 0; k < 4; ++k){
      bf8 b = *(const bf8*)&wt_g[(s*16 + lm)*128 + k*32 + lg*8];
      D = mfma16(a[k], b, D);
    }
    gmx[s] = fmaxf(fmaxf(D[0], D[1]), fmaxf(D[2], D[3]));
  }

  // bounce theta + g through LDS (xt region reused)
  __syncthreads();                     // all frag reads of xt done
  u16t* tl = &xt[0][0];                // theta [64][72] u16 (4608)
  u16t* gl = &xt[0][0] + 4608;         // g     [64][20] u16 (1280)
  #pragma unroll
  for (int s = 0; s < 4; ++s){
    #pragma unroll
    for (int r = 0; r < 4; ++r)
      tl[(w*16 + lg*4 + r)*72 + s*16 + lm] = f2bf(Dth[s][r]);
    gl[(s*16 + lm)*20 + 4*w + lg] = f2bf(gmx[s]);
  }
  __syncthreads();
  { // theta: coalesced b128 row stores
    u16t* th = theta + (size_t)batch * NQ * 64;
    #pragma unroll
    for (int p = 0; p < 2; ++p){
      int slot = t + 256*p;            // 512 slots = 64 rows x 8 pieces
      int row = slot >> 3, piece = slot & 7;
      int q = QROW(row);
      *(bf8*)&th[(size_t)q*64 + piece*8] = *(const bf8*)&tl[row*72 + piece*8];
    }
  }
  { // g: permuted 8B chunk stores. thread t -> (channel c, L)
    u16t* gt = g_t + (size_t)batch * 64 * NKV;
    int c = t >> 2, L = t & 3;
    int T = (kvbase >> 4) & 3;
    int kvg = kvbase & ~63;
    u16x4v v;
    #pragma unroll
    for (int u = 0; u < 4; ++u) v[u] = gl[c*20 + L*4 + u];
    *(u16x4v*)&gt[(size_t)c*NKV + kvg + (T>>1)*32 + ((T&1)<<2) + L*8] = v;
  }
}

// ---------------------------------------------------------------------------
// Kernel 3: fused attention + W-conv + BN + residual.
// 256 blocks (1/CU), 384 threads = 6 waves = 3 q-tiles(48q, M_rep=3) x 2 kh.
// Swapped QK leaves P k-slots lane-resident; g_t's sigma-permuted layout
// makes the PV fragments match WITHOUT any P LDS bounce or shuffle.
// Triple-buffered global_load_lds staging, counted vmcnt, raw s_barriers.
// ---------------------------------------------------------------------------
#define PHI_OFF 0
#define G_OFF   49152
#define SCRAP_OFF 98304
#define Y_OFF   76800

__global__ __launch_bounds__(384) void attn_fused(
    const u16t* __restrict__ theta, const u16t* __restrict__ phi,
    const u16t* __restrict__ g_t, const u16t* __restrict__ wt_W,
    const float* __restrict__ alpha, const float* __restrict__ beta2,
    const float* __restrict__ x, float* __restrict__ out)
{
  // loop:  [0,49152) phi [kh][3buf][8KB]; [49152,98304) g; [98304,102400) scrap
  // epi:   yp f32 [144][68] @0 ; y_lds u16 [144][72] @76800 ;
  //        out_lds f32 [144][130] @0
  __shared__ __align__(16) char SM[102400];
  __shared__ float sums[2][144];

  const int bid = blockIdx.x;
  const int blk = (bid & 7)*32 + (bid >> 3);   // XCD chunk swizzle (256=8x32)
  const int batch = blk >> 6;
  const int qb = (blk & 63) * 144;
  const int t = threadIdx.x;
  const int w = t >> 6, l = t & 63, lm = l & 15, lg = l >> 4;
  const int qw = w >> 1, kh = w & 1;

  // theta B-frags (queries qb + qw*48 .. +47)
  const u16t* th = theta + ((size_t)batch*NQ + qb)*64;
  bf8 a[3][2];
  #pragma unroll
  for (int mr = 0; mr < 3; ++mr){
    a[mr][0] = *(const bf8*)&th[(qw*48 + mr*16 + lm)*64 + lg*8];
    a[mr][1] = *(const bf8*)&th[(qw*48 + mr*16 + lm)*64 + 32 + lg*8];
  }
  asm volatile("s_waitcnt vmcnt(0)" ::: "memory");

  const char* phc = (const char*)(phi + (size_t)batch*NKV*64);
  const char* gtc = (const char*)(g_t + (size_t)batch*64*NKV);

  // stage one kt step into buffer bufc: 36 units of 1KB, 6 per wave (4 dummy)
  auto STAGE = [&](int kt_s, int bufc){
    #pragma unroll
    for (int j = 0; j < 6; ++j){
      int u = w*6 + j;
      int ur = (u < 32) ? u : (u - 32);
      int khu = ur >> 4, isg = (ur >> 3) & 1, sub = ur & 7;
      int row = sub*8 + (l >> 3);
      int swz = ((l & 7) ^ (l >> 3)) << 4;
      int kb = (khu*18 + kt_s) * 64;
      char* dst = (u < 32)
        ? SM + (isg ? G_OFF : PHI_OFF) + (khu*3 + bufc)*8192 + sub*1024 + l*16
        : SM + SCRAP_OFF + (u - 32)*1024 + l*16;
      const char* src = isg
        ? gtc + (size_t)row*(NKV*2) + (size_t)kb*2 + swz
        : phc + (size_t)(kb + row)*128 + swz;
      GLDS16(src, dst);
    }
  };

  f4 Y[3][4];
  #pragma unroll
  for (int mr = 0; mr < 3; ++mr)
    #pragma unroll
    for (int s = 0; s < 4; ++s)
      Y[mr][s] = f4{0.f, 0.f, 0.f, 0.f};
  float lsum[3] = {0.f, 0.f, 0.f};

  STAGE(0, 0);
  STAGE(1, 1);

  int bufc = 0;
  for (int kt = 0; kt < 18; ++kt){
    __builtin_amdgcn_s_barrier();      // compute(kt-1) done; buf kt+2 free
    if (kt < 16){
      STAGE(kt + 2, (bufc == 0) ? 2 : bufc - 1);
      asm volatile("s_waitcnt vmcnt(12)" ::: "memory");   // stage(kt) landed
    } else if (kt == 16){
      asm volatile("s_waitcnt vmcnt(6)" ::: "memory");
    } else {
      asm volatile("s_waitcnt vmcnt(0)" ::: "memory");
    }
    __builtin_amdgcn_s_barrier();      // all waves' stage(kt) landed

    const char* pb = SM + PHI_OFF + (kh*3 + bufc)*8192;
    const char* gb = SM + G_OFF   + (kh*3 + bufc)*8192;
    const int m7 = lm & 7;

    // phi frags (swizzled read)
    bf8 bp[4][2];
    #pragma unroll
    for (int tt = 0; tt < 4; ++tt){
      int rb = (tt*16 + lm)*128;
      bp[tt][0] = *(const bf8*)(pb + rb + ((lg ^ m7) << 4));
      bp[tt][1] = *(const bf8*)(pb + rb + (((4 + lg) ^ m7) << 4));
    }
    // g frags (sigma-permuted rows -> match register P k-slots)
    bf8 bg[4][2];
    #pragma unroll
    for (int s = 0; s < 4; ++s){
      int rb = (s*16 + lm)*128;
      bg[s][0] = *(const bf8*)(gb + rb + ((lg ^ m7) << 4));
      bg[s][1] = *(const bf8*)(gb + rb + (((4 + lg) ^ m7) << 4));
    }

    #pragma unroll
    for (int mr = 0; mr < 3; ++mr){
      // swapped QK: lane holds S[key tt*16+lg*4+r][query lm]
      f4 S[4];
      __builtin_amdgcn_s_setprio(1);
      #pragma unroll
      for (int tt = 0; tt < 4; ++tt){
        f4 z = {0.f, 0.f, 0.f, 0.f};
        z = mfma16(bp[tt][0], a[mr][0], z);
        S[tt] = mfma16(bp[tt][1], a[mr][1], z);
      }
      __builtin_amdgcn_s_setprio(0);
      // P = exp(S-30) in-register -> PV A-frags via cvt_pk (zero shuffles)
      u32t wq[8];
      #pragma unroll
      for (int tt = 0; tt < 4; ++tt){
        float p0, p1, p2, p3;
        float a0 = fmaf(S[tt][0], 1.44269504f, -43.2808512f);
        float a1 = fmaf(S[tt][1], 1.44269504f, -43.2808512f);
        float a2 = fmaf(S[tt][2], 1.44269504f, -43.2808512f);
        float a3 = fmaf(S[tt][3], 1.44269504f, -43.2808512f);
        asm("v_exp_f32 %0, %1" : "=v"(p0) : "v"(a0));
        asm("v_exp_f32 %0, %1" : "=v"(p1) : "v"(a1));
        asm("v_exp_f32 %0, %1" : "=v"(p2) : "v"(a2));
        asm("v_exp_f32 %0, %1" : "=v"(p3) : "v"(a3));
        lsum[mr] += (p0 + p1) + (p2 + p3);
        asm("v_cvt_pk_bf16_f32 %0, %1, %2" : "=v"(wq[tt*2])   : "v"(p0), "v"(p1));
        asm("v_cvt_pk_bf16_f32 %0, %1, %2" : "=v"(wq[tt*2+1]) : "v"(p2), "v"(p3));
      }
      bf8 pa0 = __builtin_bit_cast(bf8, u32x4{wq[0], wq[1], wq[2], wq[3]});
      bf8 pa1 = __builtin_bit_cast(bf8, u32x4{wq[4], wq[5], wq[6], wq[7]});
      // PV
      __builtin_amdgcn_s_setprio(1);
      #pragma unroll
      for (int s = 0; s < 4; ++s){
        Y[mr][s] = mfma16(pa0, bg[s][0], Y[mr][s]);
        Y[mr][s] = mfma16(pa1, bg[s][1], Y[mr][s]);
      }
      __builtin_amdgcn_s_setprio(0);
    }
    bufc = (bufc == 2) ? 0 : bufc + 1;
  }

  // per-query sums (reduce over lg groups)
  #pragma unroll
  for (int mr = 0; mr < 3; ++mr){
    float sv = lsum[mr];
    sv += __shfl_xor(sv, 16);
    sv += __shfl_xor(sv, 32);
    if (lg == 0) sums[kh][qw*48 + mr*16 + lm] = sv;
  }

  __syncthreads();                       // stage region dead -> yp [144][68]
  float (*yp)[68] = (float (*)[68])SM;
  if (kh == 0){
    #pragma unroll
    for (int mr = 0; mr < 3; ++mr)
      #pragma unroll
      for (int s = 0; s < 4; ++s)
        #pragma unroll
        for (int r = 0; r < 4; ++r)
          yp[qw*48 + mr*16 + lg*4 + r][s*16 + lm] = Y[mr][s][r];
  }
  __syncthreads();
  if (kh == 1){
    #pragma unroll
    for (int mr = 0; mr < 3; ++mr)
      #pragma unroll
      for (int s = 0; s < 4; ++s)
        #pragma unroll
        for (int r = 0; r < 4; ++r)
          yp[qw*48 + mr*16 + lg*4 + r][s*16 + lm] += Y[mr][s][r];
  }
  __syncthreads();

  // normalize -> bf16 y_lds [144][72]
  u16t* yl = (u16t*)(SM + Y_OFF);
  #pragma unroll
  for (int i = 0; i < 12; ++i){
    int p = t + 384*i;            // 4608 pairs = 144q x 32
    int q = p >> 5, cp = p & 31;
    float tot = sums[0][q] + sums[1][q];
    float inv = 1.0f / tot;
    float v0 = yp[q][cp*2] * inv;
    float v1 = yp[q][cp*2 + 1] * inv;
    u32t pk;
    asm("v_cvt_pk_bf16_f32 %0, %1, %2" : "=v"(pk) : "v"(v0), "v"(v1));
    *(u32t*)&yl[q*72 + cp*2] = pk;
  }
  __syncthreads();

  // W conv: 72 tiles (9 qt x 8 ct) over 6 waves
  float (*ol)[130] = (float (*)[130])SM;
  #pragma unroll
  for (int i = 0; i < 12; ++i){
    int tau = w + 6*i;            // 0..71
    int qt = tau >> 3, ct = tau & 7;
    bf8 ya0 = *(const bf8*)&yl[(qt*16 + lm)*72 + lg*8];
    bf8 ya1 = *(const bf8*)&yl[(qt*16 + lm)*72 + 32 + lg*8];
    const u16t* wr = wt_W + (ct*16 + lm)*64;
    bf8 b0 = *(const bf8*)&wr[lg*8];
    bf8 b1 = *(const bf8*)&wr[lg*8 + 32];
    f4 z = {0.f, 0.f, 0.f, 0.f};
    z = mfma16(ya0, b0, z);
    z = mfma16(ya1, b1, z);
    #pragma unroll
    for (int r = 0; r < 4; ++r)
      ol[qt*16 + lg*4 + r][ct*16 + lm] = z[r];
  }
  __syncthreads();

  // BN + residual; float4 stores (144q = 36 float4 per channel)
  const float* xb = x + (size_t)batch*NC*NQ + qb;
  float* ob = out + (size_t)batch*NC*NQ + qb;
  #pragma unroll
  for (int i = 0; i < 12; ++i){
    int idx = t + 384*i;          // < 4608 = 128c x 36
    int c = idx / 36, qv = idx % 36;
    float4 xv = *(const float4*)&xb[(size_t)c*NQ + qv*4];
    float al = alpha[c], be = beta2[c];
    float4 ov;
    ov.x = ol[qv*4 + 0][c]*al + be + xv.x;
    ov.y = ol[qv*4 + 1][c]*al + be + xv.y;
    ov.z = ol[qv*4 + 2][c]*al + be + xv.z;
    ov.w = ol[qv*4 + 3][c]*al + be + xv.w;
    *(float4*)&ob[(size_t)c*NQ + qv*4] = ov;
  }
}

// ---------------------------------------------------------------------------
extern "C" void kernel_launch(void* const* d_in, const int* in_sizes, int n_in,
                              void* d_out, int out_size, void* d_ws, size_t ws_size,
                              hipStream_t stream)
{
  const float* x       = (const float*)d_in[0];
  const float* g_w     = (const float*)d_in[1];
  const float* g_b     = (const float*)d_in[2];
  const float* theta_w = (const float*)d_in[3];
  const float* theta_b = (const float*)d_in[4];
  const float* phi_w   = (const float*)d_in[5];
  const float* phi_b   = (const float*)d_in[6];
  const float* W_w     = (const float*)d_in[7];
  const float* W_b     = (const float*)d_in[8];
  const float* bn_g    = (const float*)d_in[9];
  const float* bn_b    = (const float*)d_in[10];
  const float* bn_m    = (const float*)d_in[11];
  const float* bn_v    = (const float*)d_in[12];
  float* out = (float*)d_out;

  char* ws = (char*)d_ws;
  size_t off = 0;
  u16t* theta = (u16t*)(ws + off); off += (size_t)NB*NQ*64*2;
  u16t* phi   = (u16t*)(ws + off); off += (size_t)NB*NKV*64*2;
  u16t* g_t   = (u16t*)(ws + off); off += (size_t)NB*64*NKV*2;
  u16t* wt_theta = (u16t*)(ws + off); off += 64*128*2;
  u16t* wt_phi   = (u16t*)(ws + off); off += 64*128*2;
  u16t* wt_g     = (u16t*)(ws + off); off += 64*128*2;
  u16t* wt_W     = (u16t*)(ws + off); off += 128*64*2;
  float* alpha = (float*)(ws + off); off += 128*4;
  float* beta2 = (float*)(ws + off); off += 128*4;
  if (off > ws_size) return;

  prep_weights<<<32, 256, 0, stream>>>(g_w, theta_w, phi_w, W_w, W_b,
                                       bn_g, bn_b, bn_m, bn_v,
                                       wt_theta, wt_phi, wt_g, wt_W, alpha, beta2);
  conv3_pool<<<576, 256, 0, stream>>>(x, wt_theta, wt_phi, wt_g,
                                      theta_b, phi_b, g_b, theta, phi, g_t);
  attn_fused<<<256, 384, 0, stream>>>(theta, phi, g_t, wt_W, alpha, beta2, x, out);
}